// Round 1
// 819.917 us; speedup vs baseline: 1.0700x; 1.0700x over previous
//
#include <hip/hip_runtime.h>

#define Bdim 8
#define Ddim 64
#define Hdim 384
#define Wdim 512

// Tile geometry: one block = 4 rows x 64 cols, 256 threads = 4 waves,
// each wave covers one full 64-wide row segment (256-B aligned loads/stores).
#define TH 4
#define TW 64
#define TILES_W (Wdim / TW)               // 8
#define TILES_H (Hdim / TH)               // 96
#define TILES_PER_B (TILES_W * TILES_H)   // 768

// tw lives in the LOW 3 bits of blockIdx: vertically adjacent tiles differ by
// exactly 8 in blockIdx -> same XCD under round-robin dispatch -> the shared
// boundary row (y1 of tile th == y0 of tile th+1) is an L2 hit, not an HBM refetch.

__global__ __launch_bounds__(256, 8) void resample2d_kernel(
    const float* __restrict__ img,   // (B, D, H, W)
    const float* __restrict__ flow,  // (B, 2, H, W)
    float* __restrict__ out)         // (B, D, H, W)
{
    const int HW = Hdim * Wdim;

    int bid = blockIdx.x;
    int b   = bid / TILES_PER_B;
    int s   = bid - b * TILES_PER_B;
    int th  = s >> 3;                 // tile row   (0..95)
    int tw  = s & 7;                  // tile col   (0..7) -> XCD id under round-robin

    int lane = threadIdx.x & 63;
    int wv   = threadIdx.x >> 6;

    int h  = th * TH + wv;
    int w  = tw * TW + lane;
    int hw = h * Wdim + w;

    // flow: read-once stream, don't cache-pollute
    const float* fb = flow + (size_t)b * 2 * HW;
    float u = __builtin_nontemporal_load(fb + hw);
    float v = __builtin_nontemporal_load(fb + HW + hw);

    float fx = fminf(fmaxf((float)w + u, 0.0f), (float)(Wdim - 1));
    float fy = fminf(fmaxf((float)h + v, 0.0f), (float)(Hdim - 1));
    float x0f = floorf(fx);
    float y0f = floorf(fy);
    float wx = fx - x0f;
    float wy = fy - y0f;
    int x0 = (int)x0f;
    int y0 = (int)y0f;
    int x1 = min(x0 + 1, Wdim - 1);
    int y1 = min(y0 + 1, Hdim - 1);

    float w00 = (1.0f - wy) * (1.0f - wx);
    float w01 = (1.0f - wy) * wx;
    float w10 = wy * (1.0f - wx);
    float w11 = wy * wx;

    // per-lane 32-bit element indices; per-d pointer stays wave-uniform (SGPR),
    // so loads/stores compile to SADDR + 32-bit voffset (no per-lane 64-b addr regs)
    int i00 = y0 * Wdim + x0;
    int i01 = y0 * Wdim + x1;
    int i10 = y1 * Wdim + x0;
    int i11 = y1 * Wdim + x1;

    const float* ib = img + (size_t)b * Ddim * HW;
    float*       ob = out + (size_t)b * Ddim * HW;

    for (int d0 = 0; d0 < Ddim; d0 += 8) {
        float v00[8], v01[8], v10[8], v11[8];
        #pragma unroll
        for (int dd = 0; dd < 8; ++dd) {
            const float* p = ib + (size_t)(d0 + dd) * HW;
            v00[dd] = p[i00];
            v01[dd] = p[i01];
            v10[dd] = p[i10];
            v11[dd] = p[i11];
        }
        #pragma unroll
        for (int dd = 0; dd < 8; ++dd) {
            float r = v00[dd] * w00 + v01[dd] * w01
                    + v10[dd] * w10 + v11[dd] * w11;
            // output is never re-read: non-temporal store keeps L2 free for the stencil
            __builtin_nontemporal_store(r, ob + (size_t)(d0 + dd) * HW + hw);
        }
    }
}

extern "C" void kernel_launch(void* const* d_in, const int* in_sizes, int n_in,
                              void* d_out, int out_size, void* d_ws, size_t ws_size,
                              hipStream_t stream) {
    const float* img  = (const float*)d_in[0];
    const float* flow = (const float*)d_in[1];
    float* out = (float*)d_out;

    const int total_blocks = Bdim * TILES_PER_B;  // 6144
    dim3 block(256);
    dim3 grid(total_blocks);
    resample2d_kernel<<<grid, block, 0, stream>>>(img, flow, out);
}

// Round 2
// 743.325 us; speedup vs baseline: 1.1802x; 1.1030x over previous
//
#include <hip/hip_runtime.h>

#define Bdim 8
#define Ddim 64
#define Hdim 384
#define Wdim 512

// Tile geometry: one block = 4 rows x 64 cols, 256 threads = 4 waves,
// each wave covers one full 64-wide row segment (256-B aligned stores).
#define TH 4
#define TW 64
#define TILES_W (Wdim / TW)               // 8
#define TILES_H (Hdim / TH)               // 96
#define TILES_PER_B (TILES_W * TILES_H)   // 768

// tw in the LOW 3 bits of blockIdx: vertically adjacent tiles differ by 8
// in blockIdx -> same XCD under round-robin dispatch -> shared boundary row
// is an L2 hit (this held: FETCH dropped 855->338 MB in R1).

__global__ __launch_bounds__(256, 8) void resample2d_kernel(
    const float* __restrict__ img,   // (B, D, H, W)
    const float* __restrict__ flow,  // (B, 2, H, W)
    float* __restrict__ out)         // (B, D, H, W)
{
    const int HW = Hdim * Wdim;

    int bid = blockIdx.x;
    int b   = bid / TILES_PER_B;
    int s   = bid - b * TILES_PER_B;
    int th  = s >> 3;                 // tile row   (0..95)
    int tw  = s & 7;                  // tile col   (0..7) -> XCD id

    int lane = threadIdx.x & 63;
    int wv   = threadIdx.x >> 6;

    int h  = th * TH + wv;
    int w  = tw * TW + lane;
    int hw = h * Wdim + w;

    const float* fb = flow + (size_t)b * 2 * HW;
    float u = __builtin_nontemporal_load(fb + hw);
    float v = __builtin_nontemporal_load(fb + HW + hw);

    float fx = fminf(fmaxf((float)w + u, 0.0f), (float)(Wdim - 1));
    float fy = fminf(fmaxf((float)h + v, 0.0f), (float)(Hdim - 1));

    // Fold the x1/y1 clamp into the weight: x0 <= W-2 so the pair (x0, x0+1)
    // is ALWAYS in-bounds and contiguous -> one float2 gather per row tap.
    // At fx == W-1: x0 = W-2, wx = 1.0 -> result = p[W-1] exactly (matches ref).
    int x0 = min((int)floorf(fx), Wdim - 2);
    int y0 = min((int)floorf(fy), Hdim - 2);
    float wx = fx - (float)x0;
    float wy = fy - (float)y0;

    float w00 = (1.0f - wy) * (1.0f - wx);
    float w01 = (1.0f - wy) * wx;
    float w10 = wy * (1.0f - wx);
    float w11 = wy * wx;

    // Per-lane byte offsets of the two row-pairs; per-d base stays wave-uniform.
    int o0 = (y0 * Wdim + x0) * 4;        // row y0, 8-byte pair at 4-B alignment
    int o1 = o0 + Wdim * 4;               // row y0+1

    const char* ibc = (const char*)(img + (size_t)b * Ddim * HW);
    float*      ob  = out + (size_t)b * Ddim * HW + hw;

    for (int d0 = 0; d0 < Ddim; d0 += 8) {
        float2 r0[8], r1[8];
        #pragma unroll
        for (int dd = 0; dd < 8; ++dd) {
            const char* p = ibc + (size_t)(d0 + dd) * (HW * 4);
            r0[dd] = *(const float2*)(p + o0);   // global_load_dwordx2
            r1[dd] = *(const float2*)(p + o1);
        }
        #pragma unroll
        for (int dd = 0; dd < 8; ++dd) {
            float r = r0[dd].x * w00 + r0[dd].y * w01
                    + r1[dd].x * w10 + r1[dd].y * w11;
            __builtin_nontemporal_store(r, ob + (size_t)(d0 + dd) * HW);
        }
    }
}

extern "C" void kernel_launch(void* const* d_in, const int* in_sizes, int n_in,
                              void* d_out, int out_size, void* d_ws, size_t ws_size,
                              hipStream_t stream) {
    const float* img  = (const float*)d_in[0];
    const float* flow = (const float*)d_in[1];
    float* out = (float*)d_out;

    const int total_blocks = Bdim * TILES_PER_B;  // 6144
    dim3 block(256);
    dim3 grid(total_blocks);
    resample2d_kernel<<<grid, block, 0, stream>>>(img, flow, out);
}